// Round 12
// baseline (46.387 us; speedup 1.0000x reference)
//
#include <hip/hip_runtime.h>
#include <math.h>

#define NN 1000
#define NIT 1
#define NKT 16

typedef _Float16 f16;
typedef _Float16 f16x8 __attribute__((ext_vector_type(8)));
typedef _Float16 f16x4 __attribute__((ext_vector_type(4)));
typedef float    f32x4 __attribute__((ext_vector_type(4)));

// ---------------- workspace offsets ----------------
// f32 units:
#define WS_H1P 0
#define WS_H1T 1024
#define WS_H2P 2048
#define WS_H2T 3072
#define WS_TS  4096
#define WS_XI  5120
// f16 units (relative to (f16*)d_ws):
#define WF_H1  802816               // f16 [256][1024]
#define WF_H2  1064960              // f16 [256][1024]
#define WF_BT1 1327104              // f16 [1024][1024]
#define WF_BT2 2375680
#define WF_BT3 3424256

// ---------------- output float offsets ----------------
#define O_X0    0
#define O_STEP  256000
#define O_EPS   511744
#define O_VAR   512000
#define O_TS    768000
#define O_ALPHA 1024000
#define O_BETA  1024256
#define O_POWR  1024512

// ================= conversion body =================
__device__ __forceinline__ void conv_bt_body(int idx, const float* __restrict__ W, int K0, int NW,
                                             f16* __restrict__ BT, float (*T)[32][33])
{
    const int tid = threadIdx.x;
    const int tx = tid & 31, ty = tid >> 5;
    const int kt = (idx & 31) * 32, ntile = (idx >> 5) * 32;
    #pragma unroll
    for (int i = 0; i < 4; ++i) {
        int k = kt + ty + i * 8, n = ntile + tx;
        (*T)[ty + i * 8][tx] = (k < K0 && n < NW) ? W[(size_t)k * NW + n] : 0.f;
    }
    __syncthreads();
    #pragma unroll
    for (int i = 0; i < 4; ++i) {
        int n = ntile + ty + i * 8, k = kt + tx;
        BT[(size_t)n * 1024 + k] = (f16)(*T)[tx][ty + i * 8];
    }
}

// ================= small-MLP bodies =================
__device__ __forceinline__ void l1_body(int sub, const float* __restrict__ pin,
    const float* __restrict__ pw1, const float* __restrict__ pb1,
    const float* __restrict__ ptime, const float* __restrict__ tw1, const float* __restrict__ tb1,
    float* __restrict__ ws, float* sin_)
{
    const int tid = threadIdx.x;
    const bool tp = sub >= 4;
    const float* in = tp ? ptime : pin;
    const float* W  = tp ? tw1 : pw1;
    const float* B  = tp ? tb1 : pb1;
    float* outp = ws + (tp ? WS_H1T : WS_H1P);
    const int bxl = sub & 3;
    if (tid < 64) sin_[tid] = in[tid];
    __syncthreads();
    const int u = bxl * 256 + tid;
    float acc = B[u];
    #pragma unroll 16
    for (int k = 0; k < 64; ++k) acc += sin_[k] * W[k * 1024 + u];
    outp[u] = fmaxf(acc, 0.f);
}

__device__ __forceinline__ void l2_body(int lb, const float* __restrict__ pw2, const float* __restrict__ pb2,
    const float* __restrict__ tw2, const float* __restrict__ tb2, float* __restrict__ ws,
    float (*red)[16][17])
{
    const bool tp = lb >= 64;
    const float* h = ws + (tp ? WS_H1T : WS_H1P);
    const float* W = tp ? tw2 : pw2;
    const float* B = tp ? tb2 : pb2;
    float* outp = ws + (tp ? WS_H2T : WS_H2P);
    const int u0 = (lb & 63) * 16;
    const int tid = threadIdx.x, ul = tid & 15, kc = tid >> 4;
    const float* wp = W + u0 + ul;
    float acc = 0.f;
    const int kbase = kc * 64;
    #pragma unroll 8
    for (int k = 0; k < 64; ++k) acc += h[kbase + k] * wp[(size_t)(kbase + k) * 1024];
    (*red)[kc][ul] = acc; __syncthreads();
    for (int s = 8; s; s >>= 1) { if (kc < s) (*red)[kc][ul] += (*red)[kc + s][ul]; __syncthreads(); }
    if (tid < 16) outp[u0 + tid] = fmaxf((*red)[0][tid] + B[u0 + tid], 0.f);
}

__device__ __forceinline__ void l3_body(int lb, const float* __restrict__ pw3, const float* __restrict__ pb3,
    const float* __restrict__ tw3, const float* __restrict__ tb3,
    float* __restrict__ ws, float* __restrict__ out,
    float (*red)[16][17], float* redx)
{
    const int tid = threadIdx.x;
    if (lb == 64) {
        const float* h2p = ws + WS_H2P;
        float p[3] = {0.f, 0.f, 0.f};
        for (int k = tid; k < 1024; k += 256) {
            float h = h2p[k];
            p[0] += h * pw3[k * 3 + 0];
            p[1] += h * pw3[k * 3 + 1];
            p[2] += h * pw3[k * 3 + 2];
        }
        float xi[3];
        #pragma unroll
        for (int j = 0; j < 3; ++j) {
            redx[tid] = p[j]; __syncthreads();
            for (int s = 128; s > 0; s >>= 1) {
                if (tid < s) redx[tid] += redx[tid + s];
                __syncthreads();
            }
            xi[j] = redx[0] + pb3[j];
            __syncthreads();
        }
        float alpha = xi[0], beta = xi[1];
        float powr = 1.f / (1.f + expf(-xi[2]));
        if (tid == 0) { ws[WS_XI + 0] = alpha; ws[WS_XI + 1] = beta; ws[WS_XI + 2] = powr; }
        out[O_ALPHA + tid] = alpha;
        out[O_BETA  + tid] = beta;
        out[O_POWR  + tid] = powr;
    } else {
        const float* h = ws + WS_H2T;
        const int u0 = lb * 16;
        const int ul = tid & 15, kc = tid >> 4;
        const int u = u0 + ul;
        float acc = 0.f;
        const int kbase = kc * 64;
        if (u < NN) {
            #pragma unroll 8
            for (int k = 0; k < 64; ++k) acc += h[kbase + k] * tw3[(size_t)(kbase + k) * NN + u];
        }
        (*red)[kc][ul] = acc; __syncthreads();
        for (int s = 8; s; s >>= 1) { if (kc < s) (*red)[kc][ul] += (*red)[kc + s][ul]; __syncthreads(); }
        if (tid < 16 && u0 + tid < NN) ws[WS_TS + u0 + tid] = (*red)[0][tid] + tb3[u0 + tid];
    }
}

// ================= f16 MFMA GEMM body (single-barrier dbuf; A from f16 or f32) =================
template<bool AF16, bool F16OUT>
__device__ __forceinline__ void gemm16_body(int bx,
    const f16* __restrict__ Ah, const float* __restrict__ Af, int ldA, int K0,
    const f16* __restrict__ BT,
    const float* __restrict__ bias, int NW, f16* __restrict__ Cf16, float* __restrict__ Cf32, int ldc,
    f16 (*As)[32][72], f16 (*Bs)[32][72])
{
    const int tid = threadIdx.x;
    const int lane = tid & 63, wave = tid >> 6;
    const int wm = wave >> 1, wn = wave & 1;
    const int m0 = (bx >> 5) * 32, n0 = (bx & 31) * 32;
    const int srow = tid >> 3, sc = tid & 7;
    const float4* gB = (const float4*)(BT + (size_t)(n0 + srow) * 1024 + sc * 8);

    auto loadA = [&](int t, f16x8& o) {
        if constexpr (AF16) {
            o = *(const f16x8*)(Ah + (size_t)(m0 + srow) * ldA + t * 64 + sc * 8);
        } else {
            float4 x = {0.f,0.f,0.f,0.f}, y = {0.f,0.f,0.f,0.f};
            const int k0 = t * 64 + sc * 8;
            if (k0 < K0) {                          // 8-chunk granularity (K0 % 8 == 0)
                const float* p = Af + (size_t)(m0 + srow) * ldA + k0;
                x = *(const float4*)p;
                y = *(const float4*)(p + 4);
            }
            f16x8 h = {(f16)x.x,(f16)x.y,(f16)x.z,(f16)x.w,
                       (f16)y.x,(f16)y.y,(f16)y.z,(f16)y.w};
            o = h;
        }
    };

    f32x4 acc = {0.f, 0.f, 0.f, 0.f};

    f16x8 ra; float4 rb;
    loadA(0, ra); rb = gB[0];
    *(f16x8*)&As[0][srow][sc * 8] = ra;
    *(float4*)&Bs[0][srow][sc * 8] = rb;
    loadA(1, ra); rb = gB[8];
    __syncthreads();

    const int arow = wm * 16 + (lane & 15);
    const int brow = wn * 16 + (lane & 15);
    const int kf = (lane >> 4) * 8;

    #pragma unroll 2
    for (int t = 0; t < NKT; ++t) {
        const int cur = t & 1;
        f16x8 ra2; float4 rb2 = {};
        if (t + 2 < NKT) { loadA(t + 2, ra2); rb2 = gB[(t + 2) * 8]; }

        const f16x8 a0 = *(const f16x8*)&As[cur][arow][kf];
        const f16x8 b0 = *(const f16x8*)&Bs[cur][brow][kf];
        acc = __builtin_amdgcn_mfma_f32_16x16x32_f16(a0, b0, acc, 0, 0, 0);
        const f16x8 a1 = *(const f16x8*)&As[cur][arow][32 + kf];
        const f16x8 b1 = *(const f16x8*)&Bs[cur][brow][32 + kf];
        acc = __builtin_amdgcn_mfma_f32_16x16x32_f16(a1, b1, acc, 0, 0, 0);

        if (t + 1 < NKT) {
            *(f16x8*)&As[cur ^ 1][srow][sc * 8] = ra;
            *(float4*)&Bs[cur ^ 1][srow][sc * 8] = rb;
        }
        ra = ra2; rb = rb2;
        __syncthreads();
    }

    const int col = n0 + wn * 16 + (lane & 15);
    const int row = m0 + wm * 16 + (lane >> 4) * 4;
    const float bs = (col < NW) ? bias[col] : 0.f;
    #pragma unroll
    for (int j = 0; j < 4; ++j) {
        float v = acc[j] + bs;
        if (F16OUT) {
            v = fmaxf(v, 0.f);
            Cf16[(size_t)(row + j) * 1024 + col] = (f16)v;
        } else if (col < NW) {
            Cf32[(size_t)(row + j) * ldc + col] = v;
        }
    }
}

// ================= K1: conv nw1 + l1 =================
__global__ __launch_bounds__(256) void k_s1(const float* __restrict__ nw1,
    const float* __restrict__ pin, const float* __restrict__ pw1, const float* __restrict__ pb1,
    const float* __restrict__ ptime, const float* __restrict__ tw1, const float* __restrict__ tb1,
    float* __restrict__ ws, f16* __restrict__ wsh)
{
    __shared__ float T[32][33];
    __shared__ float sin_[64];
    const int bx = blockIdx.x;
    if (bx < 1024) {
        conv_bt_body(bx, nw1, 1000, 1024, wsh + WF_BT1, &T);
    } else {
        l1_body(bx - 1024, pin, pw1, pb1, ptime, tw1, tb1, ws, sin_);
    }
}

// ================= K2: gemm1 (A direct from net_iv f32) + conv nw2 + l2 =================
__global__ __launch_bounds__(256) void k_s2(const float* __restrict__ net_iv,
    const float* __restrict__ nw2, const float* __restrict__ nb1,
    const float* __restrict__ pw2, const float* __restrict__ pb2,
    const float* __restrict__ tw2, const float* __restrict__ tb2,
    float* __restrict__ ws, f16* __restrict__ wsh)
{
    __shared__ f16 As[2][32][72];
    __shared__ f16 Bs[2][32][72];
    __shared__ float T[32][33];
    __shared__ float red[16][17];
    const int bx = blockIdx.x;
    if (bx < 256) {
        gemm16_body<false, true>(bx, nullptr, net_iv, 1000, 1000, wsh + WF_BT1,
                                 nb1, 1024, wsh + WF_H1, nullptr, 0, As, Bs);
    } else if (bx < 1280) {
        conv_bt_body(bx - 256, nw2, 1024, 1024, wsh + WF_BT2, &T);
    } else {
        l2_body(bx - 1280, pw2, pb2, tw2, tb2, ws, &red);
    }
}

// ================= K3: gemm2 + conv nw3 + l3/xi =================
__global__ __launch_bounds__(256) void k_s3(const float* __restrict__ nw3, const float* __restrict__ nb2,
    const float* __restrict__ pw3, const float* __restrict__ pb3,
    const float* __restrict__ tw3, const float* __restrict__ tb3,
    float* __restrict__ ws, f16* __restrict__ wsh, float* __restrict__ out)
{
    __shared__ f16 As[2][32][72];
    __shared__ f16 Bs[2][32][72];
    __shared__ float T[32][33];
    __shared__ float red[16][17];
    __shared__ float redx[256];
    const int bx = blockIdx.x;
    if (bx < 256) {
        gemm16_body<true, true>(bx, wsh + WF_H1, nullptr, 1024, 1024, wsh + WF_BT2,
                                nb2, 1024, wsh + WF_H2, nullptr, 0, As, Bs);
    } else if (bx < 1280) {
        conv_bt_body(bx - 256, nw3, 1024, 1000, wsh + WF_BT3, &T);
    } else {
        l3_body(bx - 1280, pw3, pb3, tw3, tb3, ws, out, &red, redx);
    }
}

// ================= K4: gemm3 (var -> out) + ts/step broadcast writers =================
__global__ __launch_bounds__(256) void k_s4(const float* __restrict__ nb3,
    const float* __restrict__ ws, f16* __restrict__ wsh, float* __restrict__ out)
{
    __shared__ f16 As[2][32][72];
    __shared__ f16 Bs[2][32][72];
    const int bx = blockIdx.x;
    if (bx < 256) {
        gemm16_body<true, false>(bx, wsh + WF_H2, nullptr, 1024, 1024, wsh + WF_BT3,
                                 nb3, 1000, nullptr, out + O_VAR, 1000, As, Bs);
    } else {
        const int b = bx - 256;                    // one block per batch
        const int tid = threadIdx.x;
        if (tid < 250) {
            const float4 tv = *(const float4*)&ws[WS_TS + tid * 4];
            *(float4*)&out[O_TS + b * NN + tid * 4] = tv;
        }
        #pragma unroll
        for (int k = 0; k < 4; ++k) {
            int i = tid * 4 + k;
            if (i < NN - 1) out[O_STEP + b * (NN - 1) + i] = 0.001f;
        }
    }
}

// ================= K5: ODE solve (f64, NIT=1, x0+eps only) =================
__device__ inline void d_shift_left(const double a[4], double b4[4], double* sh, int tid, double pad)
{
    __syncthreads();
    sh[tid] = a[0];
    __syncthreads();
    b4[0] = a[1]; b4[1] = a[2]; b4[2] = a[3];
    b4[3] = (tid < 255) ? sh[tid + 1] : pad;
}
__device__ inline void d_scan_fwd(const double a[4], double incl[4], double* swt, int tid)
{
    double p0 = a[0], p1 = p0 + a[1], p2 = p1 + a[2], p3 = p2 + a[3];
    int lane = tid & 63, wid = tid >> 6;
    double w = p3;
    #pragma unroll
    for (int d = 1; d < 64; d <<= 1) {
        double t = __shfl_up(w, d, 64);
        if (lane >= d) w += t;
    }
    __syncthreads();
    if (lane == 63) swt[wid] = w;
    __syncthreads();
    double off = w - p3;
    #pragma unroll
    for (int q = 0; q < 3; ++q) if (q < wid) off += swt[q];
    incl[0] = p0 + off; incl[1] = p1 + off; incl[2] = p2 + off; incl[3] = p3 + off;
}
__device__ inline void d_scan_rev(const double a[4], double incl[4], double* swt, int tid)
{
    double s3 = a[3], s2 = s3 + a[2], s1 = s2 + a[1], s0 = s1 + a[0];
    int lane = tid & 63, wid = tid >> 6;
    double w = s0;
    #pragma unroll
    for (int d = 1; d < 64; d <<= 1) {
        double t = __shfl_down(w, d, 64);
        if (lane < 64 - d) w += t;
    }
    __syncthreads();
    if (lane == 0) swt[wid] = w;
    __syncthreads();
    double off = w - s0;
    #pragma unroll
    for (int q = 1; q < 4; ++q) if (q > wid) off += swt[q];
    incl[0] = s0 + off; incl[1] = s1 + off; incl[2] = s2 + off; incl[3] = s3 + off;
}

__global__ __launch_bounds__(256) void k_ode(const float* __restrict__ ws, float* __restrict__ out)
{
    const int b = blockIdx.x;
    const int tid = threadIdx.x;
    const double H = 0.001, H2c = 0.5e-6, INVH = 1000.0, EPSR = 1e-8;

    __shared__ double sh[257];
    __shared__ double sh2[257];
    __shared__ double swt[4];

    const float alpha = ws[WS_XI + 0], beta = ws[WS_XI + 1], powr = ws[WS_XI + 2];

    const float4 tsv = *(const float4*)&ws[WS_TS + tid * 4];
    const float* varp = out + O_VAR + (size_t)b * NN;
    float vaa[4];
    #pragma unroll
    for (int k = 0; k < 4; ++k) {
        int i = tid * 4 + k;
        vaa[k] = (i < NN) ? varp[i] : 0.f;
    }
    const double init = (double)varp[0];

    float tsa[4] = {tsv.x, tsv.y, tsv.z, tsv.w};

    double r[4];
    #pragma unroll
    for (int k = 0; k < 4; ++k) {
        int i = tid * 4 + k;
        float tf = tsa[k], vf = vaa[k];
        float basef = fabsf(alpha * tf + beta * tf * tf);
        float rr = powf(basef, powr) * vf * vf + tf;
        r[k] = (i < NN) ? (double)rr : 0.0;
    }

    double rn[4];
    d_shift_left(r, rn, sh, tid, 0.0);
    double ux[4], ud[4], us[4], g[4], gi[4];
    #pragma unroll
    for (int k = 0; k < 4; ++k) {
        int i = tid * 4 + k;
        ud[k] = r[k];
        us[k] = (i < NN - 1) ? (rn[k] - r[k]) * INVH : 0.0;
        g[k]  = (i < NN - 1) ? 0.5 * H * (r[k] + rn[k]) : 0.0;
    }
    d_scan_fwd(g, gi, swt, tid);
    #pragma unroll
    for (int k = 0; k < 4; ++k) {
        int i = tid * 4 + k;
        ux[k] = (i < NN) ? (init + (gi[k] - g[k])) : 0.0;
    }

    double tx[4] = {0,0,0,0}, td[4] = {0,0,0,0}, tss[4] = {0,0,0,0};
    for (int it = 0; it < NIT; ++it) {
        double a[4], yx0 = 0.0;
        #pragma unroll
        for (int k = 0; k < 4; ++k) {
            int i = tid * 4 + k;
            double yx = ux[k] - EPSR * tx[k];
            if (k == 0) yx0 = yx;
            a[k] = (i == 0) ? 0.0 : yx;
        }
        double S[4]; d_scan_rev(a, S, swt, tid);
        double wP[4];
        #pragma unroll
        for (int k = 0; k < 4; ++k) wP[k] = S[k] - a[k];
        double wV[4];
        #pragma unroll
        for (int k = 0; k < 4; ++k) {
            int i = tid * 4 + k;
            double ys = us[k] - EPSR * tss[k];
            wV[k] = (i < NN - 1) ? -(ys + H2c * wP[k]) * INVH : 0.0;
        }
        __syncthreads();
        sh[tid] = wV[3];
        if (tid == 0) sh[256] = yx0 + wP[0];
        __syncthreads();
        double wVm[4];
        wVm[1] = wV[0]; wVm[2] = wV[1]; wVm[3] = wV[2];
        wVm[0] = (tid > 0) ? sh[tid - 1] : 0.0;
        const double w0 = sh[256];

        double wD[4];
        #pragma unroll
        for (int k = 0; k < 4; ++k) {
            int i = tid * 4 + k;
            double yd = ud[k] - EPSR * td[k];
            wD[k] = (i < NN) ? (yd + ((i < NN - 1) ? H * wP[k] : 0.0) - wVm[k] + wV[k]) : 0.0;
        }
        double wDn[4]; d_shift_left(wD, wDn, sh, tid, 0.0);
        #pragma unroll
        for (int k = 0; k < 4; ++k) {
            int i = tid * 4 + k;
            td[k]  = wD[k];
            tss[k] = (i < NN - 1) ? (wDn[k] - wD[k] - wV[k]) * INVH : 0.0;
            g[k]   = (i < NN - 1) ? (H * td[k] + H2c * tss[k] + wP[k]) : 0.0;
        }
        d_scan_fwd(g, gi, swt, tid);
        #pragma unroll
        for (int k = 0; k < 4; ++k) {
            int i = tid * 4 + k;
            tx[k] = (i < NN) ? (w0 + (gi[k] - g[k])) : 0.0;
        }
    }

    double dx[4], dd[4], ds_[4];
    #pragma unroll
    for (int k = 0; k < 4; ++k) { dx[k] = -EPSR * tx[k]; dd[k] = -EPSR * td[k]; ds_[k] = -EPSR * tss[k]; }

    if (tid < 250) {
        float4 xv;
        xv.x = (float)(ux[0] + dx[0]); xv.y = (float)(ux[1] + dx[1]);
        xv.z = (float)(ux[2] + dx[2]); xv.w = (float)(ux[3] + dx[3]);
        *(float4*)&out[O_X0 + b * NN + tid * 4] = xv;
    }

    // eps = ||A*Delta||; dual shift in one barrier pair
    __syncthreads();
    sh[tid] = dx[0]; sh2[tid] = dd[0];
    __syncthreads();
    double dxn[4], ddn[4];
    dxn[0] = dx[1]; dxn[1] = dx[2]; dxn[2] = dx[3];
    dxn[3] = (tid < 255) ? sh[tid + 1] : 0.0;
    ddn[0] = dd[1]; ddn[1] = dd[2]; ddn[2] = dd[3];
    ddn[3] = (tid < 255) ? sh2[tid + 1] : 0.0;

    double ss = 0.0;
    #pragma unroll
    for (int k = 0; k < 4; ++k) {
        int i = tid * 4 + k;
        if (i < NN) ss += dd[k] * dd[k];
        if (i == 0) ss += dx[k] * dx[k];
        if (i < NN - 1) {
            double rp = dxn[k] - dx[k] - H * dd[k] - H2c * ds_[k];
            double rv = ddn[k] - dd[k] - H * ds_[k];
            ss += rp * rp + rv * rv;
        }
    }
    const int lane = tid & 63, wid = tid >> 6;
    #pragma unroll
    for (int d = 32; d; d >>= 1) ss += __shfl_down(ss, d, 64);
    __syncthreads();
    if (lane == 0) swt[wid] = ss;
    __syncthreads();
    if (tid == 0) out[O_EPS + b] = (float)sqrt(swt[0] + swt[1] + swt[2] + swt[3]);
}

// ================= launcher =================
extern "C" void kernel_launch(void* const* d_in, const int* in_sizes, int n_in,
                              void* d_out, int out_size, void* d_ws, size_t ws_size,
                              hipStream_t stream)
{
    const float* pin    = (const float*)d_in[0];
    const float* ptime  = (const float*)d_in[1];
    const float* pw1    = (const float*)d_in[2];
    const float* pb1    = (const float*)d_in[3];
    const float* pw2    = (const float*)d_in[4];
    const float* pb2    = (const float*)d_in[5];
    const float* pw3    = (const float*)d_in[6];
    const float* pb3    = (const float*)d_in[7];
    const float* tw1    = (const float*)d_in[8];
    const float* tb1    = (const float*)d_in[9];
    const float* tw2    = (const float*)d_in[10];
    const float* tb2    = (const float*)d_in[11];
    const float* tw3    = (const float*)d_in[12];
    const float* tb3    = (const float*)d_in[13];
    const float* nw1    = (const float*)d_in[14];
    const float* nb1    = (const float*)d_in[15];
    const float* nw2    = (const float*)d_in[16];
    const float* nb2    = (const float*)d_in[17];
    const float* nw3    = (const float*)d_in[18];
    const float* nb3    = (const float*)d_in[19];
    const float* net_iv = (const float*)d_in[20];
    float* out = (float*)d_out;
    float* ws  = (float*)d_ws;
    f16*   wsh = (f16*)d_ws;

    k_s1 <<<1032, 256, 0, stream>>>(nw1, pin, pw1, pb1, ptime, tw1, tb1, ws, wsh);
    k_s2 <<<1408, 256, 0, stream>>>(net_iv, nw2, nb1, pw2, pb2, tw2, tb2, ws, wsh);
    k_s3 <<<1345, 256, 0, stream>>>(nw3, nb2, pw3, pb3, tw3, tb3, ws, wsh, out);
    k_s4 <<<512,  256, 0, stream>>>(nb3, ws, wsh, out);
    k_ode<<<256,  256, 0, stream>>>(ws, out);
}

// Round 13
// 39.727 us; speedup vs baseline: 1.1676x; 1.1676x over previous
//
#include <hip/hip_runtime.h>
#include <math.h>

#define NN 1000
#define NIT 1
#define NKT 16

typedef _Float16 f16;
typedef _Float16 f16x8 __attribute__((ext_vector_type(8)));
typedef _Float16 f16x4 __attribute__((ext_vector_type(4)));
typedef float    f32x4 __attribute__((ext_vector_type(4)));

// ---------------- workspace offsets ----------------
// f32 units:
#define WS_H1P 0
#define WS_H1T 1024
#define WS_H2P 2048
#define WS_H2T 3072
#define WS_TS  4096
#define WS_XI  5120
// f16 units (relative to (f16*)d_ws):
#define WF_A0  540672               // f16 [256][1024]
#define WF_H1  802816               // f16 [256][1024]
#define WF_H2  1064960              // f16 [256][1024]
#define WF_BT1 1327104              // f16 [1024][1024]
#define WF_BT2 2375680
#define WF_BT3 3424256

// ---------------- output float offsets ----------------
#define O_X0    0
#define O_STEP  256000
#define O_EPS   511744
#define O_VAR   512000
#define O_TS    768000
#define O_ALPHA 1024000
#define O_BETA  1024256
#define O_POWR  1024512

// ================= conversion bodies =================
__device__ __forceinline__ void conv_bt_body(int idx, const float* __restrict__ W, int K0, int NW,
                                             f16* __restrict__ BT, float (*T)[32][33])
{
    const int tid = threadIdx.x;
    const int tx = tid & 31, ty = tid >> 5;
    const int kt = (idx & 31) * 32, ntile = (idx >> 5) * 32;
    #pragma unroll
    for (int i = 0; i < 4; ++i) {
        int k = kt + ty + i * 8, n = ntile + tx;
        (*T)[ty + i * 8][tx] = (k < K0 && n < NW) ? W[(size_t)k * NW + n] : 0.f;
    }
    __syncthreads();
    #pragma unroll
    for (int i = 0; i < 4; ++i) {
        int n = ntile + ty + i * 8, k = kt + tx;
        BT[(size_t)n * 1024 + k] = (f16)(*T)[tx][ty + i * 8];
    }
}

__device__ __forceinline__ void conv_a_body(int row, const float* __restrict__ in, f16* __restrict__ a0)
{
    const int t = threadIdx.x;
    float4 v = {0.f, 0.f, 0.f, 0.f};
    if (t < 250) v = ((const float4*)(in + row * 1000))[t];
    f16x4 h = {(f16)v.x, (f16)v.y, (f16)v.z, (f16)v.w};
    *(f16x4*)&a0[row * 1024 + t * 4] = h;
}

// ================= small-MLP bodies =================
__device__ __forceinline__ void l1_body(int sub, const float* __restrict__ pin,
    const float* __restrict__ pw1, const float* __restrict__ pb1,
    const float* __restrict__ ptime, const float* __restrict__ tw1, const float* __restrict__ tb1,
    float* __restrict__ ws, float* sin_)
{
    const int tid = threadIdx.x;
    const bool tp = sub >= 4;
    const float* in = tp ? ptime : pin;
    const float* W  = tp ? tw1 : pw1;
    const float* B  = tp ? tb1 : pb1;
    float* outp = ws + (tp ? WS_H1T : WS_H1P);
    const int bxl = sub & 3;
    if (tid < 64) sin_[tid] = in[tid];
    __syncthreads();
    const int u = bxl * 256 + tid;
    float acc = B[u];
    #pragma unroll 16
    for (int k = 0; k < 64; ++k) acc += sin_[k] * W[k * 1024 + u];
    outp[u] = fmaxf(acc, 0.f);
}

__device__ __forceinline__ void l2_body(int lb, const float* __restrict__ pw2, const float* __restrict__ pb2,
    const float* __restrict__ tw2, const float* __restrict__ tb2, float* __restrict__ ws,
    float (*red)[16][17])
{
    const bool tp = lb >= 64;
    const float* h = ws + (tp ? WS_H1T : WS_H1P);
    const float* W = tp ? tw2 : pw2;
    const float* B = tp ? tb2 : pb2;
    float* outp = ws + (tp ? WS_H2T : WS_H2P);
    const int u0 = (lb & 63) * 16;
    const int tid = threadIdx.x, ul = tid & 15, kc = tid >> 4;
    const float* wp = W + u0 + ul;
    float acc = 0.f;
    const int kbase = kc * 64;
    #pragma unroll 8
    for (int k = 0; k < 64; ++k) acc += h[kbase + k] * wp[(size_t)(kbase + k) * 1024];
    (*red)[kc][ul] = acc; __syncthreads();
    for (int s = 8; s; s >>= 1) { if (kc < s) (*red)[kc][ul] += (*red)[kc + s][ul]; __syncthreads(); }
    if (tid < 16) outp[u0 + tid] = fmaxf((*red)[0][tid] + B[u0 + tid], 0.f);
}

__device__ __forceinline__ void l3_body(int lb, const float* __restrict__ pw3, const float* __restrict__ pb3,
    const float* __restrict__ tw3, const float* __restrict__ tb3,
    float* __restrict__ ws, float* __restrict__ out,
    float (*red)[16][17], float* redx)
{
    const int tid = threadIdx.x;
    if (lb == 64) {
        const float* h2p = ws + WS_H2P;
        float p[3] = {0.f, 0.f, 0.f};
        for (int k = tid; k < 1024; k += 256) {
            float h = h2p[k];
            p[0] += h * pw3[k * 3 + 0];
            p[1] += h * pw3[k * 3 + 1];
            p[2] += h * pw3[k * 3 + 2];
        }
        float xi[3];
        #pragma unroll
        for (int j = 0; j < 3; ++j) {
            redx[tid] = p[j]; __syncthreads();
            for (int s = 128; s > 0; s >>= 1) {
                if (tid < s) redx[tid] += redx[tid + s];
                __syncthreads();
            }
            xi[j] = redx[0] + pb3[j];
            __syncthreads();
        }
        float alpha = xi[0], beta = xi[1];
        float powr = 1.f / (1.f + expf(-xi[2]));
        if (tid == 0) { ws[WS_XI + 0] = alpha; ws[WS_XI + 1] = beta; ws[WS_XI + 2] = powr; }
        out[O_ALPHA + tid] = alpha;
        out[O_BETA  + tid] = beta;
        out[O_POWR  + tid] = powr;
    } else {
        const float* h = ws + WS_H2T;
        const int u0 = lb * 16;
        const int ul = tid & 15, kc = tid >> 4;
        const int u = u0 + ul;
        float acc = 0.f;
        const int kbase = kc * 64;
        if (u < NN) {
            #pragma unroll 8
            for (int k = 0; k < 64; ++k) acc += h[kbase + k] * tw3[(size_t)(kbase + k) * NN + u];
        }
        (*red)[kc][ul] = acc; __syncthreads();
        for (int s = 8; s; s >>= 1) { if (kc < s) (*red)[kc][ul] += (*red)[kc + s][ul]; __syncthreads(); }
        if (tid < 16 && u0 + tid < NN) ws[WS_TS + u0 + tid] = (*red)[0][tid] + tb3[u0 + tid];
    }
}

// ================= f16 MFMA GEMM body (single-barrier double-buffer) =================
template<bool F16OUT>
__device__ __forceinline__ void gemm16_body(int bx, const f16* __restrict__ A, const f16* __restrict__ BT,
    const float* __restrict__ bias, int NW, f16* __restrict__ Cf16, float* __restrict__ Cf32, int ldc,
    f16 (*As)[32][72], f16 (*Bs)[32][72])
{
    const int tid = threadIdx.x;
    const int lane = tid & 63, wave = tid >> 6;
    const int wm = wave >> 1, wn = wave & 1;
    const int m0 = (bx >> 5) * 32, n0 = (bx & 31) * 32;
    const int srow = tid >> 3, sc = tid & 7;
    const float4* gA = (const float4*)(A  + (size_t)(m0 + srow) * 1024 + sc * 8);
    const float4* gB = (const float4*)(BT + (size_t)(n0 + srow) * 1024 + sc * 8);

    f32x4 acc = {0.f, 0.f, 0.f, 0.f};

    float4 ra = gA[0], rb = gB[0];
    *(float4*)&As[0][srow][sc * 8] = ra;
    *(float4*)&Bs[0][srow][sc * 8] = rb;
    ra = gA[8]; rb = gB[8];
    __syncthreads();

    const int arow = wm * 16 + (lane & 15);
    const int brow = wn * 16 + (lane & 15);
    const int kf = (lane >> 4) * 8;

    #pragma unroll 2
    for (int t = 0; t < NKT; ++t) {
        const int cur = t & 1;
        float4 ra2 = {}, rb2 = {};
        if (t + 2 < NKT) { ra2 = gA[(t + 2) * 8]; rb2 = gB[(t + 2) * 8]; }

        const f16x8 a0 = *(const f16x8*)&As[cur][arow][kf];
        const f16x8 b0 = *(const f16x8*)&Bs[cur][brow][kf];
        acc = __builtin_amdgcn_mfma_f32_16x16x32_f16(a0, b0, acc, 0, 0, 0);
        const f16x8 a1 = *(const f16x8*)&As[cur][arow][32 + kf];
        const f16x8 b1 = *(const f16x8*)&Bs[cur][brow][32 + kf];
        acc = __builtin_amdgcn_mfma_f32_16x16x32_f16(a1, b1, acc, 0, 0, 0);

        if (t + 1 < NKT) {
            *(float4*)&As[cur ^ 1][srow][sc * 8] = ra;
            *(float4*)&Bs[cur ^ 1][srow][sc * 8] = rb;
        }
        ra = ra2; rb = rb2;
        __syncthreads();
    }

    const int col = n0 + wn * 16 + (lane & 15);
    const int row = m0 + wm * 16 + (lane >> 4) * 4;
    const float bs = (col < NW) ? bias[col] : 0.f;
    #pragma unroll
    for (int j = 0; j < 4; ++j) {
        float v = acc[j] + bs;
        if (F16OUT) {
            v = fmaxf(v, 0.f);
            Cf16[(size_t)(row + j) * 1024 + col] = (f16)v;
        } else if (col < NW) {
            Cf32[(size_t)(row + j) * ldc + col] = v;
        }
    }
}

// ================= K1: conv nw1 + conv A0 + l1 =================
__global__ __launch_bounds__(256) void k_s1(const float* __restrict__ nw1, const float* __restrict__ net_iv,
    const float* __restrict__ pin, const float* __restrict__ pw1, const float* __restrict__ pb1,
    const float* __restrict__ ptime, const float* __restrict__ tw1, const float* __restrict__ tb1,
    float* __restrict__ ws, f16* __restrict__ wsh)
{
    __shared__ float T[32][33];
    __shared__ float sin_[64];
    const int bx = blockIdx.x;
    if (bx < 1024) {
        conv_bt_body(bx, nw1, 1000, 1024, wsh + WF_BT1, &T);
    } else if (bx < 1280) {
        conv_a_body(bx - 1024, net_iv, wsh + WF_A0);
    } else {
        l1_body(bx - 1280, pin, pw1, pb1, ptime, tw1, tb1, ws, sin_);
    }
}

// ================= K2: gemm1 + conv nw2 + l2 =================
__global__ __launch_bounds__(256) void k_s2(const float* __restrict__ nw2, const float* __restrict__ nb1,
    const float* __restrict__ pw2, const float* __restrict__ pb2,
    const float* __restrict__ tw2, const float* __restrict__ tb2,
    float* __restrict__ ws, f16* __restrict__ wsh)
{
    __shared__ f16 As[2][32][72];
    __shared__ f16 Bs[2][32][72];
    __shared__ float T[32][33];
    __shared__ float red[16][17];
    const int bx = blockIdx.x;
    if (bx < 256) {
        gemm16_body<true>(bx, wsh + WF_A0, wsh + WF_BT1, nb1, 1024, wsh + WF_H1, nullptr, 0, As, Bs);
    } else if (bx < 1280) {
        conv_bt_body(bx - 256, nw2, 1024, 1024, wsh + WF_BT2, &T);
    } else {
        l2_body(bx - 1280, pw2, pb2, tw2, tb2, ws, &red);
    }
}

// ================= K3: gemm2 + conv nw3 + l3/xi =================
__global__ __launch_bounds__(256) void k_s3(const float* __restrict__ nw3, const float* __restrict__ nb2,
    const float* __restrict__ pw3, const float* __restrict__ pb3,
    const float* __restrict__ tw3, const float* __restrict__ tb3,
    float* __restrict__ ws, f16* __restrict__ wsh, float* __restrict__ out)
{
    __shared__ f16 As[2][32][72];
    __shared__ f16 Bs[2][32][72];
    __shared__ float T[32][33];
    __shared__ float red[16][17];
    __shared__ float redx[256];
    const int bx = blockIdx.x;
    if (bx < 256) {
        gemm16_body<true>(bx, wsh + WF_H1, wsh + WF_BT2, nb2, 1024, wsh + WF_H2, nullptr, 0, As, Bs);
    } else if (bx < 1280) {
        conv_bt_body(bx - 256, nw3, 1024, 1000, wsh + WF_BT3, &T);
    } else {
        l3_body(bx - 1280, pw3, pb3, tw3, tb3, ws, out, &red, redx);
    }
}

// ================= K4: gemm3 (var -> out) + ts/step broadcast writers =================
__global__ __launch_bounds__(256) void k_s4(const float* __restrict__ nb3,
    const float* __restrict__ ws, f16* __restrict__ wsh, float* __restrict__ out)
{
    __shared__ f16 As[2][32][72];
    __shared__ f16 Bs[2][32][72];
    const int bx = blockIdx.x;
    if (bx < 256) {
        gemm16_body<false>(bx, wsh + WF_H2, wsh + WF_BT3, nb3, 1000,
                           nullptr, out + O_VAR, 1000, As, Bs);
    } else {
        const int b = bx - 256;                    // one block per batch
        const int tid = threadIdx.x;
        #pragma unroll
        for (int k = 0; k < 4; ++k) {
            int i = tid * 4 + k;
            if (i < NN)     out[O_TS   + b * NN + i]       = ws[WS_TS + i];
            if (i < NN - 1) out[O_STEP + b * (NN - 1) + i] = 0.001f;
        }
    }
}

// ================= K5: ODE solve (f64, NIT=1, x0+eps only) =================
__device__ inline void d_shift_left(const double a[4], double b4[4], double* sh, int tid, double pad)
{
    __syncthreads();
    sh[tid] = a[0];
    __syncthreads();
    b4[0] = a[1]; b4[1] = a[2]; b4[2] = a[3];
    b4[3] = (tid < 255) ? sh[tid + 1] : pad;
}
__device__ inline void d_scan_fwd(const double a[4], double incl[4], double* swt, int tid)
{
    double p0 = a[0], p1 = p0 + a[1], p2 = p1 + a[2], p3 = p2 + a[3];
    int lane = tid & 63, wid = tid >> 6;
    double w = p3;
    #pragma unroll
    for (int d = 1; d < 64; d <<= 1) {
        double t = __shfl_up(w, d, 64);
        if (lane >= d) w += t;
    }
    __syncthreads();
    if (lane == 63) swt[wid] = w;
    __syncthreads();
    double off = w - p3;
    #pragma unroll
    for (int q = 0; q < 3; ++q) if (q < wid) off += swt[q];
    incl[0] = p0 + off; incl[1] = p1 + off; incl[2] = p2 + off; incl[3] = p3 + off;
}
__device__ inline void d_scan_rev(const double a[4], double incl[4], double* swt, int tid)
{
    double s3 = a[3], s2 = s3 + a[2], s1 = s2 + a[1], s0 = s1 + a[0];
    int lane = tid & 63, wid = tid >> 6;
    double w = s0;
    #pragma unroll
    for (int d = 1; d < 64; d <<= 1) {
        double t = __shfl_down(w, d, 64);
        if (lane < 64 - d) w += t;
    }
    __syncthreads();
    if (lane == 0) swt[wid] = w;
    __syncthreads();
    double off = w - s0;
    #pragma unroll
    for (int q = 1; q < 4; ++q) if (q > wid) off += swt[q];
    incl[0] = s0 + off; incl[1] = s1 + off; incl[2] = s2 + off; incl[3] = s3 + off;
}

__global__ __launch_bounds__(256) void k_ode(const float* __restrict__ ws, float* __restrict__ out)
{
    const int b = blockIdx.x;
    const int tid = threadIdx.x;
    const double H = 0.001, H2c = 0.5e-6, INVH = 1000.0, EPSR = 1e-8;

    __shared__ double sh[257];
    __shared__ double sh2[257];
    __shared__ double swt[4];

    const float alpha = ws[WS_XI + 0], beta = ws[WS_XI + 1], powr = ws[WS_XI + 2];

    const float4 tsv = *(const float4*)&ws[WS_TS + tid * 4];
    const float* varp = out + O_VAR + (size_t)b * NN;
    float vaa[4];
    #pragma unroll
    for (int k = 0; k < 4; ++k) {
        int i = tid * 4 + k;
        vaa[k] = (i < NN) ? varp[i] : 0.f;
    }
    const double init = (double)varp[0];

    float tsa[4] = {tsv.x, tsv.y, tsv.z, tsv.w};

    double r[4];
    #pragma unroll
    for (int k = 0; k < 4; ++k) {
        int i = tid * 4 + k;
        float tf = tsa[k], vf = vaa[k];
        float basef = fabsf(alpha * tf + beta * tf * tf);
        float rr = powf(basef, powr) * vf * vf + tf;
        r[k] = (i < NN) ? (double)rr : 0.0;
    }

    double rn[4];
    d_shift_left(r, rn, sh, tid, 0.0);
    double ux[4], ud[4], us[4], g[4], gi[4];
    #pragma unroll
    for (int k = 0; k < 4; ++k) {
        int i = tid * 4 + k;
        ud[k] = r[k];
        us[k] = (i < NN - 1) ? (rn[k] - r[k]) * INVH : 0.0;
        g[k]  = (i < NN - 1) ? 0.5 * H * (r[k] + rn[k]) : 0.0;
    }
    d_scan_fwd(g, gi, swt, tid);
    #pragma unroll
    for (int k = 0; k < 4; ++k) {
        int i = tid * 4 + k;
        ux[k] = (i < NN) ? (init + (gi[k] - g[k])) : 0.0;
    }

    double tx[4] = {0,0,0,0}, td[4] = {0,0,0,0}, tss[4] = {0,0,0,0};
    for (int it = 0; it < NIT; ++it) {
        double a[4], yx0 = 0.0;
        #pragma unroll
        for (int k = 0; k < 4; ++k) {
            int i = tid * 4 + k;
            double yx = ux[k] - EPSR * tx[k];
            if (k == 0) yx0 = yx;
            a[k] = (i == 0) ? 0.0 : yx;
        }
        double S[4]; d_scan_rev(a, S, swt, tid);
        double wP[4];
        #pragma unroll
        for (int k = 0; k < 4; ++k) wP[k] = S[k] - a[k];
        double wV[4];
        #pragma unroll
        for (int k = 0; k < 4; ++k) {
            int i = tid * 4 + k;
            double ys = us[k] - EPSR * tss[k];
            wV[k] = (i < NN - 1) ? -(ys + H2c * wP[k]) * INVH : 0.0;
        }
        __syncthreads();
        sh[tid] = wV[3];
        if (tid == 0) sh[256] = yx0 + wP[0];
        __syncthreads();
        double wVm[4];
        wVm[1] = wV[0]; wVm[2] = wV[1]; wVm[3] = wV[2];
        wVm[0] = (tid > 0) ? sh[tid - 1] : 0.0;
        const double w0 = sh[256];

        double wD[4];
        #pragma unroll
        for (int k = 0; k < 4; ++k) {
            int i = tid * 4 + k;
            double yd = ud[k] - EPSR * td[k];
            wD[k] = (i < NN) ? (yd + ((i < NN - 1) ? H * wP[k] : 0.0) - wVm[k] + wV[k]) : 0.0;
        }
        double wDn[4]; d_shift_left(wD, wDn, sh, tid, 0.0);
        #pragma unroll
        for (int k = 0; k < 4; ++k) {
            int i = tid * 4 + k;
            td[k]  = wD[k];
            tss[k] = (i < NN - 1) ? (wDn[k] - wD[k] - wV[k]) * INVH : 0.0;
            g[k]   = (i < NN - 1) ? (H * td[k] + H2c * tss[k] + wP[k]) : 0.0;
        }
        d_scan_fwd(g, gi, swt, tid);
        #pragma unroll
        for (int k = 0; k < 4; ++k) {
            int i = tid * 4 + k;
            tx[k] = (i < NN) ? (w0 + (gi[k] - g[k])) : 0.0;
        }
    }

    double dx[4], dd[4], ds_[4];
    #pragma unroll
    for (int k = 0; k < 4; ++k) { dx[k] = -EPSR * tx[k]; dd[k] = -EPSR * td[k]; ds_[k] = -EPSR * tss[k]; }

    #pragma unroll
    for (int k = 0; k < 4; ++k) {
        int i = tid * 4 + k;
        if (i < NN) out[O_X0 + b * NN + i] = (float)(ux[k] + dx[k]);
    }

    // eps = ||A*Delta||; dual shift in one barrier pair
    __syncthreads();
    sh[tid] = dx[0]; sh2[tid] = dd[0];
    __syncthreads();
    double dxn[4], ddn[4];
    dxn[0] = dx[1]; dxn[1] = dx[2]; dxn[2] = dx[3];
    dxn[3] = (tid < 255) ? sh[tid + 1] : 0.0;
    ddn[0] = dd[1]; ddn[1] = dd[2]; ddn[2] = dd[3];
    ddn[3] = (tid < 255) ? sh2[tid + 1] : 0.0;

    double ss = 0.0;
    #pragma unroll
    for (int k = 0; k < 4; ++k) {
        int i = tid * 4 + k;
        if (i < NN) ss += dd[k] * dd[k];
        if (i == 0) ss += dx[k] * dx[k];
        if (i < NN - 1) {
            double rp = dxn[k] - dx[k] - H * dd[k] - H2c * ds_[k];
            double rv = ddn[k] - dd[k] - H * ds_[k];
            ss += rp * rp + rv * rv;
        }
    }
    const int lane = tid & 63, wid = tid >> 6;
    #pragma unroll
    for (int d = 32; d; d >>= 1) ss += __shfl_down(ss, d, 64);
    __syncthreads();
    if (lane == 0) swt[wid] = ss;
    __syncthreads();
    if (tid == 0) out[O_EPS + b] = (float)sqrt(swt[0] + swt[1] + swt[2] + swt[3]);
}

// ================= launcher =================
extern "C" void kernel_launch(void* const* d_in, const int* in_sizes, int n_in,
                              void* d_out, int out_size, void* d_ws, size_t ws_size,
                              hipStream_t stream)
{
    const float* pin    = (const float*)d_in[0];
    const float* ptime  = (const float*)d_in[1];
    const float* pw1    = (const float*)d_in[2];
    const float* pb1    = (const float*)d_in[3];
    const float* pw2    = (const float*)d_in[4];
    const float* pb2    = (const float*)d_in[5];
    const float* pw3    = (const float*)d_in[6];
    const float* pb3    = (const float*)d_in[7];
    const float* tw1    = (const float*)d_in[8];
    const float* tb1    = (const float*)d_in[9];
    const float* tw2    = (const float*)d_in[10];
    const float* tb2    = (const float*)d_in[11];
    const float* tw3    = (const float*)d_in[12];
    const float* tb3    = (const float*)d_in[13];
    const float* nw1    = (const float*)d_in[14];
    const float* nb1    = (const float*)d_in[15];
    const float* nw2    = (const float*)d_in[16];
    const float* nb2    = (const float*)d_in[17];
    const float* nw3    = (const float*)d_in[18];
    const float* nb3    = (const float*)d_in[19];
    const float* net_iv = (const float*)d_in[20];
    float* out = (float*)d_out;
    float* ws  = (float*)d_ws;
    f16*   wsh = (f16*)d_ws;

    k_s1 <<<1288, 256, 0, stream>>>(nw1, net_iv, pin, pw1, pb1, ptime, tw1, tb1, ws, wsh);
    k_s2 <<<1408, 256, 0, stream>>>(nw2, nb1, pw2, pb2, tw2, tb2, ws, wsh);
    k_s3 <<<1345, 256, 0, stream>>>(nw3, nb2, pw3, pb3, tw3, tb3, ws, wsh, out);
    k_s4 <<<512,  256, 0, stream>>>(nb3, ws, wsh, out);
    k_ode<<<256,  256, 0, stream>>>(ws, out);
}